// Round 15
// baseline (726.408 us; speedup 1.0000x reference)
//
#include <hip/hip_runtime.h>
#include <hip/hip_bf16.h>

#define NN 50000
#define EE 600000
#define SREP 64   // stats replicas (atomic decontention)
#define SCB 49    // scan blocks: 49 x 1024 elems >= NN

#if __has_builtin(__builtin_amdgcn_global_atomic_fadd_v2bf16)
#define USE_PK 1
typedef short bf2v __attribute__((ext_vector_type(2)));
#else
#define USE_PK 0
#endif

typedef short bf16x8 __attribute__((ext_vector_type(8)));
typedef float f32x4 __attribute__((ext_vector_type(4)));

__device__ inline ushort f2bf(float x) {  // round-to-nearest-even bf16
  unsigned u = __float_as_uint(x);
  u = (u + 0x7fffu + ((u >> 16) & 1u)) >> 16;
  return (ushort)u;
}
__device__ inline float bflo(uint t) { return __uint_as_float(t << 16); }
__device__ inline float bfhi(uint t) { return __uint_as_float(t & 0xffff0000u); }
__device__ inline uint f22bf(float a, float b) { return ((uint)f2bf(b) << 16) | (uint)f2bf(a); }

// ---------- graph preprocessing ----------
__global__ void count2_k(const int* __restrict__ ei, int* __restrict__ cnt_s,
                         int* __restrict__ cnt_d) {
  int e = blockIdx.x * 256 + threadIdx.x;
  if (e < EE) {
    atomicAdd(&cnt_s[ei[e]], 1);
    atomicAdd(&cnt_d[ei[EE + e]], 1);
  }
}

__global__ __launch_bounds__(256) void scanA_k(const int* __restrict__ cnt,
                                               int* __restrict__ cur,
                                               int* __restrict__ bsum) {
  __shared__ int ls[256];
  const int t = threadIdx.x;
  const int base = blockIdx.x * 1024 + t * 4;
  int4 v = {0, 0, 0, 0};
  if (base + 3 < NN) v = *(const int4*)(cnt + base);
  else {
    if (base + 0 < NN) v.x = cnt[base + 0];
    if (base + 1 < NN) v.y = cnt[base + 1];
    if (base + 2 < NN) v.z = cnt[base + 2];
  }
  ls[t] = v.x + v.y + v.z + v.w;
  __syncthreads();
  for (int off = 1; off < 256; off <<= 1) {
    int u = (t >= off) ? ls[t - off] : 0;
    __syncthreads();
    ls[t] += u;
    __syncthreads();
  }
  int ex = (t == 0) ? 0 : ls[t - 1];
  int4 o;
  o.x = ex;
  o.y = ex + v.x;
  o.z = o.y + v.y;
  o.w = o.z + v.z;
  if (base + 3 < NN) *(int4*)(cur + base) = o;
  else {
    if (base + 0 < NN) cur[base + 0] = o.x;
    if (base + 1 < NN) cur[base + 1] = o.y;
    if (base + 2 < NN) cur[base + 2] = o.z;
  }
  if (t == 255) bsum[blockIdx.x] = ls[255];
}

__global__ __launch_bounds__(64) void scanB_k(int* __restrict__ bsum) {
  int t = threadIdx.x;
  int own = (t < SCB) ? bsum[t] : 0;
  int v = own;
#pragma unroll
  for (int off = 1; off < 64; off <<= 1) {
    int u = __shfl_up(v, off, 64);
    if (t >= off) v += u;
  }
  if (t < SCB) bsum[t] = v - own;
}

__global__ __launch_bounds__(256) void scanC_k(int* __restrict__ cur,
                                               const int* __restrict__ bsum,
                                               const int* __restrict__ cnt_d,
                                               float* __restrict__ invd) {
  const int t = threadIdx.x;
  const int base = blockIdx.x * 1024 + t * 4;
  const int off = bsum[blockIdx.x];
  if (base + 3 < NN) {
    int4 v = *(int4*)(cur + base);
    v.x += off; v.y += off; v.z += off; v.w += off;
    *(int4*)(cur + base) = v;
    int4 cd = *(const int4*)(cnt_d + base);
    float4 iv;
    iv.x = 1.0f / (float)max(cd.x, 1);
    iv.y = 1.0f / (float)max(cd.y, 1);
    iv.z = 1.0f / (float)max(cd.z, 1);
    iv.w = 1.0f / (float)max(cd.w, 1);
    *(float4*)(invd + base) = iv;
  } else {
    for (int i = 0; i < 4; ++i) {
      if (base + i < NN) {
        cur[base + i] += off;
        invd[base + i] = 1.0f / (float)max(cnt_d[base + i], 1);
      }
    }
  }
}

__global__ void fill_csc_k(const int* __restrict__ ei, const float* __restrict__ ew,
                           int* __restrict__ cur_s, int4* __restrict__ e4) {
  int e = blockIdx.x * 256 + threadIdx.x;
  if (e < EE) {
    int s = ei[e], d = ei[EE + e];
    int pc = atomicAdd(&cur_s[s], 1);
    int4 v;
    v.x = s; v.y = d; v.z = __float_as_int(ew[e]); v.w = 0;
    e4[pc] = v;
  }
}

// ---------- weight precompute: all 6 W matrices -> bf16 swizzled image ----
__global__ void wpk_k(const float* __restrict__ Wl0, const float* __restrict__ Wr0,
                      const float* __restrict__ Wl1, const float* __restrict__ Wr1,
                      const float* __restrict__ Wl2, const float* __restrict__ Wr2,
                      ushort* __restrict__ wbuf) {
  int idx = blockIdx.x * 256 + threadIdx.x;  // 0..81919
  const float* W; int F, r, off;
  if (idx < 16384)      { W = Wl0; F = 128; r = idx;         off = 0; }
  else if (idx < 32768) { W = Wr0; F = 128; r = idx - 16384; off = 16384; }
  else if (idx < 49152) { W = Wl1; F = 128; r = idx - 32768; off = 32768; }
  else if (idx < 65536) { W = Wr1; F = 128; r = idx - 49152; off = 49152; }
  else if (idx < 73728) { W = Wl2; F = 64;  r = idx - 65536; off = 65536; }
  else                  { W = Wr2; F = 64;  r = idx - 73728; off = 73728; }
  int k = r / F, n = r % F;
  wbuf[off + n * 128 + ((((k >> 3) + n) & 15) << 3) + (k & 7)] = f2bf(W[k * F + n]);
}

// ---------- fused MFMA dual-GEMM + edge atomics ----------
// Phase 0: Tl tile = bnrelu(H)@Wl, stored to LDS (reusing Hs — afrag is in
// registers by then). Phase 1: Trb = bnrelu(H)@Wr to global. Then this block
// issues the pk-bf16 atomics for all edges whose src lies in its 64-node
// range (CSC order guarantees a contiguous e4 range) — Tl never hits global.
template <int F, bool HB16>
__global__ __launch_bounds__(256) void gemm_agg(
    const void* __restrict__ H, const ushort* __restrict__ Wpre,
    const float* __restrict__ ss, const int4* __restrict__ e4,
    const int* __restrict__ csc_end, void* __restrict__ agg,
    ushort* __restrict__ Trb) {
  __shared__ __align__(16) ushort Wt[F * 128];
  __shared__ __align__(16) ushort Hs[64 * 128];  // H tile, then Tl tile
  const int tid = threadIdx.x;
  const int nb = blockIdx.x * 64;

  // ---- stage H tile (swizzled bf16, BN+relu if HB16)
  if (HB16) {
    for (int i = tid; i < 64 * 16; i += 256) {
      int m = i >> 4, c = i & 15;
      int node = nb + m;
      uint4 hv = {0, 0, 0, 0};
      if (node < NN) hv = ((const uint4*)H)[(size_t)node * 16 + c];
      int gk = c * 8;
      uint* p = (uint*)&hv;
#pragma unroll
      for (int j = 0; j < 4; ++j) {
        float f0 = fmaxf(fmaf(bflo(p[j]), ss[gk + 2 * j], ss[128 + gk + 2 * j]), 0.f);
        float f1 = fmaxf(fmaf(bfhi(p[j]), ss[gk + 2 * j + 1], ss[128 + gk + 2 * j + 1]), 0.f);
        p[j] = f22bf(f0, f1);
      }
      *(uint4*)&Hs[m * 128 + (((c + m) & 15) << 3)] = hv;
    }
  } else {
    for (int i = tid; i < 64 * 32; i += 256) {
      int m = i >> 5, kq = i & 31;
      int node = nb + m;
      float4 hv = {0.f, 0.f, 0.f, 0.f};
      if (node < NN) hv = ((const float4*)H)[(size_t)node * 32 + kq];
      int c = kq >> 1;
      int base = m * 128 + (((c + m) & 15) << 3) + (kq & 1) * 4;
      ushort4 u4 = {f2bf(hv.x), f2bf(hv.y), f2bf(hv.z), f2bf(hv.w)};
      *(ushort4*)&Hs[base] = u4;
    }
  }
  __syncthreads();

  const int lane = tid & 63;
  const int w = tid >> 6;
  const int col = lane & 15;
  const int quad = lane >> 4;
  const int m = w * 16 + col;

  bf16x8 afrag[4];
#pragma unroll
  for (int s = 0; s < 4; ++s) {
    int c = s * 4 + quad;
    afrag[s] = *(const bf16x8*)&Hs[m * 128 + (((c + m) & 15) << 3)];
  }
  // sync #1: all afrag preloads done — Hs may now be overwritten (phase 0
  // tile stores happen after sync #2, which is later than this for all waves)
  __syncthreads();
  for (int i = tid; i < F * 16; i += 256) ((uint4*)Wt)[i] = ((const uint4*)Wpre)[i];
  __syncthreads();  // sync #2

  // ---- phase 0: Tl tile -> LDS (plain [m][cc] layout)
#pragma unroll 2
  for (int ct = 0; ct < F / 16; ++ct) {
    int n = ct * 16 + col;
    f32x4 acc = {0.f, 0.f, 0.f, 0.f};
#pragma unroll
    for (int s = 0; s < 4; ++s) {
      int c = s * 4 + quad;
      bf16x8 b = *(const bf16x8*)&Wt[n * 128 + (((c + n) & 15) << 3)];
      acc = __builtin_amdgcn_mfma_f32_16x16x32_bf16(afrag[s], b, acc, 0, 0, 0);
    }
    int mb = w * 16 + quad * 4;
    int cc = ct * 16 + col;
#pragma unroll
    for (int r = 0; r < 4; ++r) Hs[(mb + r) * F + cc] = f2bf(acc[r]);
  }

  // ---- phase 1: Trb to global
  __syncthreads();  // all phase-0 Wt reads + tile stores complete
  for (int i = tid; i < F * 16; i += 256) ((uint4*)Wt)[i] = ((const uint4*)(Wpre + F * 128))[i];
  __syncthreads();
#pragma unroll 2
  for (int ct = 0; ct < F / 16; ++ct) {
    int n = ct * 16 + col;
    f32x4 acc = {0.f, 0.f, 0.f, 0.f};
#pragma unroll
    for (int s = 0; s < 4; ++s) {
      int c = s * 4 + quad;
      bf16x8 b = *(const bf16x8*)&Wt[n * 128 + (((c + n) & 15) << 3)];
      acc = __builtin_amdgcn_mfma_f32_16x16x32_bf16(afrag[s], b, acc, 0, 0, 0);
    }
    int nodeb = nb + w * 16 + quad * 4;
#pragma unroll
    for (int r = 0; r < 4; ++r) {
      int node = nodeb + r;
      if (node < NN) Trb[(size_t)node * F + ct * 16 + col] = f2bf(acc[r]);
    }
  }

  // ---- edge atomics for this block's src range (Tl read from LDS)
  constexpr int L = F / 2;      // uint col-pairs per edge
  constexpr int EPW = 64 / L;   // edges per wave per iter: 1 (F=128) / 2 (F=64)
  const int e0 = (nb == 0) ? 0 : csc_end[nb - 1];
  const int e1 = csc_end[min(nb + 63, NN - 1)];
  const int sub = lane / L;
  const int cp = lane % L;
  const uint* tileU = (const uint*)Hs;
  for (int j = e0 + w * EPW + sub; j < e1; j += 4 * EPW) {
    int4 p = e4[j];
    float wgt = __int_as_float(p.z);
    uint t = tileU[(p.x - nb) * L + cp];
    float f0 = wgt * bflo(t);
    float f1 = wgt * bfhi(t);
#if USE_PK
    bf2v v;
    v.x = (short)f2bf(f0);
    v.y = (short)f2bf(f1);
    __builtin_amdgcn_global_atomic_fadd_v2bf16((bf2v*)((char*)agg + ((size_t)p.y * L + cp) * 4), v);
#else
    float* a = (float*)agg + ((size_t)p.y * L + cp) * 2;
    atomicAdd(a, f0);
    atomicAdd(a + 1, f1);
#endif
  }
}

// ---------- combine: out = agg*invd + Trb + bias (+BN stats; zero agg) ----
template <int F, bool STATS, bool ZERO, bool OUTF32>
__global__ __launch_bounds__(256, 8) void combine(
    void* __restrict__ agg, const ushort* __restrict__ Trb,
    const float* __restrict__ invd, const float* __restrict__ bias,
    void* __restrict__ outp, float* __restrict__ statsb) {
  constexpr int L = F / 2;
  constexpr int NPI = 256 / L;
  constexpr int NPB = 40;  // 50000/40 = 1250 blocks exact
  const int tid = threadIdx.x;
  const int cp = tid % L;
  const int c = 2 * cp;
  const int nl = tid / L;
  const int n0 = blockIdx.x * NPB;
  const float bx = bias[c], by = bias[c + 1];
  float2 S = {0.f, 0.f}, Q = {0.f, 0.f};
#pragma unroll
  for (int it = 0; it < NPB / NPI; ++it) {
    int n = n0 + it * NPI + nl;
    float a0, a1;
#if USE_PK
    uint t = ((uint*)agg)[(size_t)n * L + cp];
    a0 = bflo(t);
    a1 = bfhi(t);
    if (ZERO) ((uint*)agg)[(size_t)n * L + cp] = 0;
#else
    float2 af = ((float2*)agg)[(size_t)n * L + cp];
    a0 = af.x;
    a1 = af.y;
    if (ZERO) { float2 z = {0.f, 0.f}; ((float2*)agg)[(size_t)n * L + cp] = z; }
#endif
    float iv = invd[n];
    uint tb = ((const uint*)Trb)[(size_t)n * L + cp];
    float2 v;
    v.x = fmaf(a0, iv, bflo(tb) + bx);
    v.y = fmaf(a1, iv, bfhi(tb) + by);
    if (OUTF32) *(float2*)((float*)outp + (size_t)n * F + c) = v;
    else ((uint*)outp)[(size_t)n * L + cp] = f22bf(v.x, v.y);
    if constexpr (STATS) {
      S.x += v.x; S.y += v.y;
      Q.x += v.x * v.x; Q.y += v.y * v.y;
    }
  }
  if constexpr (STATS) {
    __shared__ float2 sS[4][L];
    __shared__ float2 sQ[4][L];
    const int wid = tid >> 6, wl = tid & 63;
    if constexpr (L == 64) {
      sS[wid][wl] = S;
      sQ[wid][wl] = Q;
    } else {
      S.x += __shfl_xor(S.x, 32, 64); S.y += __shfl_xor(S.y, 32, 64);
      Q.x += __shfl_xor(Q.x, 32, 64); Q.y += __shfl_xor(Q.y, 32, 64);
      if (wl < 32) { sS[wid][wl] = S; sQ[wid][wl] = Q; }
    }
    __syncthreads();
    if (tid < L) {
      float2 Sa = sS[0][tid], Qa = sQ[0][tid];
#pragma unroll
      for (int w2 = 1; w2 < 4; ++w2) {
        Sa.x += sS[w2][tid].x; Sa.y += sS[w2][tid].y;
        Qa.x += sQ[w2][tid].x; Qa.y += sQ[w2][tid].y;
      }
      float* sb = statsb + (size_t)(blockIdx.x & (SREP - 1)) * 256;
      int col = 2 * tid;
      atomicAdd(&sb[col], Sa.x);
      atomicAdd(&sb[col + 1], Sa.y);
      atomicAdd(&sb[128 + col], Qa.x);
      atomicAdd(&sb[128 + col + 1], Qa.y);
    }
  }
}

// ---------- BN finalize: reduce SREP replicas, then zero them ----------
__global__ void bn_fin(float* __restrict__ statsb, const float* __restrict__ gamma,
                       const float* __restrict__ beta, float* __restrict__ ss) {
  int f = threadIdx.x;
  float sum = 0.f, sq = 0.f;
#pragma unroll 8
  for (int r = 0; r < SREP; ++r) {
    sum += statsb[r * 256 + f];
    sq  += statsb[r * 256 + 128 + f];
    statsb[r * 256 + f] = 0.f;
    statsb[r * 256 + 128 + f] = 0.f;
  }
  float mu = sum * (1.0f / (float)NN);
  float ex2 = sq * (1.0f / (float)NN);
  float var = ex2 - mu * mu;
  float sc = gamma[f] * rsqrtf(var + 1e-5f);
  ss[f] = sc;
  ss[128 + f] = beta[f] - mu * sc;
}

extern "C" void kernel_launch(void* const* d_in, const int* in_sizes, int n_in,
                              void* d_out, int out_size, void* d_ws, size_t ws_size,
                              hipStream_t stream) {
  (void)in_sizes; (void)n_in; (void)out_size; (void)ws_size;
  const float* x   = (const float*)d_in[0];
  const int*   ei  = (const int*)d_in[1];
  const float* ew  = (const float*)d_in[2];
  const float* Wl0 = (const float*)d_in[3];
  const float* Wr0 = (const float*)d_in[4];
  const float* b0  = (const float*)d_in[5];
  const float* Wl1 = (const float*)d_in[6];
  const float* Wr1 = (const float*)d_in[7];
  const float* b1  = (const float*)d_in[8];
  const float* Wl2 = (const float*)d_in[9];
  const float* Wr2 = (const float*)d_in[10];
  const float* b2  = (const float*)d_in[11];
  const float* g0  = (const float*)d_in[12];
  const float* be0 = (const float*)d_in[13];
  const float* g1  = (const float*)d_in[14];
  const float* be1 = (const float*)d_in[15];
  float* out = (float*)d_out;

  size_t off = 0;
  auto alloc = [&](size_t b) -> void* {
    void* p = (char*)d_ws + off;
    off += (b + 255) & ~(size_t)255;
    return p;
  };
  ushort* trb  = (ushort*)alloc((size_t)NN * 128 * 2);  // 12.8 MB
  ushort* hpre = (ushort*)alloc((size_t)NN * 128 * 2);  // 12.8 MB (bf16)
#if USE_PK
  const size_t AGG_B = (size_t)NN * 128 * 2;
#else
  const size_t AGG_B = (size_t)NN * 128 * 4;
#endif
  void* agg    = alloc((size_t)NN * 128 * 4);           // 25.6 MB
  int4* e4     = (int4*)alloc((size_t)EE * 16);         // 9.6 MB
  ushort* wbuf = (ushort*)alloc(81920 * 2);             // 160 KB
  int*  cnts   = (int*)alloc((size_t)NN * 2 * 4);
  int*  cnt_s  = cnts;
  int*  cnt_d  = cnts + NN;
  int*  cur_s  = (int*)alloc((size_t)NN * 4);
  int*  bsum   = (int*)alloc(SCB * 4);
  float* invd  = (float*)alloc((size_t)NN * 4);
  float* statsb = (float*)alloc((size_t)SREP * 256 * 4);
  float* ssb   = (float*)alloc(256 * 4);

  const int EB = (EE + 255) / 256;
  const int GEMMB = (NN + 63) / 64;  // 782

  // ---- prep
  hipMemsetAsync(cnts, 0, (size_t)NN * 2 * 4, stream);
  hipMemsetAsync(agg, 0, AGG_B, stream);
  hipMemsetAsync(statsb, 0, (size_t)SREP * 256 * 4, stream);
  count2_k<<<EB, 256, 0, stream>>>(ei, cnt_s, cnt_d);
  wpk_k<<<320, 256, 0, stream>>>(Wl0, Wr0, Wl1, Wr1, Wl2, Wr2, wbuf);
  scanA_k<<<SCB, 256, 0, stream>>>(cnt_s, cur_s, bsum);
  scanB_k<<<1, 64, 0, stream>>>(bsum);
  scanC_k<<<SCB, 256, 0, stream>>>(cur_s, bsum, cnt_d, invd);
  fill_csc_k<<<EB, 256, 0, stream>>>(ei, ew, cur_s, e4);
  // after fill, cur_s[n] = end offset of node n's CSC range

  // ---- layer 0 (H = x f32, no BN)
  gemm_agg<128, false><<<GEMMB, 256, 0, stream>>>(x, wbuf, nullptr, e4, cur_s, agg, trb);
  combine<128, true, true, false><<<NN / 40, 256, 0, stream>>>(agg, trb, invd, b0, hpre, statsb);
  bn_fin<<<1, 128, 0, stream>>>(statsb, g0, be0, ssb);

  // ---- layer 1 (H = hpre bf16, BN0+ReLU in staging; agg pre-zeroed by combine)
  gemm_agg<128, true><<<GEMMB, 256, 0, stream>>>(hpre, wbuf + 32768, ssb, e4, cur_s, agg, trb);
  combine<128, true, true, false><<<NN / 40, 256, 0, stream>>>(agg, trb, invd, b1, hpre, statsb);
  bn_fin<<<1, 128, 0, stream>>>(statsb, g1, be1, ssb);

  // ---- layer 2 (H = hpre bf16, BN1+ReLU in staging; out f32 to d_out)
  gemm_agg<64, true><<<GEMMB, 256, 0, stream>>>(hpre, wbuf + 65536, ssb, e4, cur_s, agg, trb);
  combine<64, false, false, true><<<NN / 40, 256, 0, stream>>>(agg, trb, invd, b2, out, nullptr);
}

// Round 16
// 611.816 us; speedup vs baseline: 1.1873x; 1.1873x over previous
//
#include <hip/hip_runtime.h>
#include <hip/hip_bf16.h>

#define NN 50000
#define EE 600000
#define SREP 64   // stats replicas (atomic decontention)
#define SCB 49    // scan blocks: 49 x 1024 elems >= NN

#if __has_builtin(__builtin_amdgcn_global_atomic_fadd_v2bf16)
#define USE_PK 1
typedef short bf2v __attribute__((ext_vector_type(2)));
#else
#define USE_PK 0
#endif

typedef short bf16x8 __attribute__((ext_vector_type(8)));
typedef float f32x4 __attribute__((ext_vector_type(4)));

__device__ inline ushort f2bf(float x) {  // round-to-nearest-even bf16
  unsigned u = __float_as_uint(x);
  u = (u + 0x7fffu + ((u >> 16) & 1u)) >> 16;
  return (ushort)u;
}
__device__ inline float bflo(uint t) { return __uint_as_float(t << 16); }
__device__ inline float bfhi(uint t) { return __uint_as_float(t & 0xffff0000u); }
__device__ inline uint f22bf(float a, float b) { return ((uint)f2bf(b) << 16) | (uint)f2bf(a); }

// ---------- graph preprocessing ----------
__global__ void count2_k(const int* __restrict__ ei, int* __restrict__ cnt_s,
                         int* __restrict__ cnt_d) {
  int e = blockIdx.x * 256 + threadIdx.x;
  if (e < EE) {
    atomicAdd(&cnt_s[ei[e]], 1);
    atomicAdd(&cnt_d[ei[EE + e]], 1);
  }
}

__global__ __launch_bounds__(256) void scanA_k(const int* __restrict__ cnt,
                                               int* __restrict__ cur,
                                               int* __restrict__ bsum) {
  __shared__ int ls[256];
  const int t = threadIdx.x;
  const int base = blockIdx.x * 1024 + t * 4;
  int4 v = {0, 0, 0, 0};
  if (base + 3 < NN) v = *(const int4*)(cnt + base);
  else {
    if (base + 0 < NN) v.x = cnt[base + 0];
    if (base + 1 < NN) v.y = cnt[base + 1];
    if (base + 2 < NN) v.z = cnt[base + 2];
  }
  ls[t] = v.x + v.y + v.z + v.w;
  __syncthreads();
  for (int off = 1; off < 256; off <<= 1) {
    int u = (t >= off) ? ls[t - off] : 0;
    __syncthreads();
    ls[t] += u;
    __syncthreads();
  }
  int ex = (t == 0) ? 0 : ls[t - 1];
  int4 o;
  o.x = ex;
  o.y = ex + v.x;
  o.z = o.y + v.y;
  o.w = o.z + v.z;
  if (base + 3 < NN) *(int4*)(cur + base) = o;
  else {
    if (base + 0 < NN) cur[base + 0] = o.x;
    if (base + 1 < NN) cur[base + 1] = o.y;
    if (base + 2 < NN) cur[base + 2] = o.z;
  }
  if (t == 255) bsum[blockIdx.x] = ls[255];
}

__global__ __launch_bounds__(64) void scanB_k(int* __restrict__ bsum) {
  int t = threadIdx.x;
  int own = (t < SCB) ? bsum[t] : 0;
  int v = own;
#pragma unroll
  for (int off = 1; off < 64; off <<= 1) {
    int u = __shfl_up(v, off, 64);
    if (t >= off) v += u;
  }
  if (t < SCB) bsum[t] = v - own;
}

__global__ __launch_bounds__(256) void scanC_k(int* __restrict__ cur,
                                               const int* __restrict__ bsum,
                                               const int* __restrict__ cnt_d,
                                               float* __restrict__ invd) {
  const int t = threadIdx.x;
  const int base = blockIdx.x * 1024 + t * 4;
  const int off = bsum[blockIdx.x];
  if (base + 3 < NN) {
    int4 v = *(int4*)(cur + base);
    v.x += off; v.y += off; v.z += off; v.w += off;
    *(int4*)(cur + base) = v;
    int4 cd = *(const int4*)(cnt_d + base);
    float4 iv;
    iv.x = 1.0f / (float)max(cd.x, 1);
    iv.y = 1.0f / (float)max(cd.y, 1);
    iv.z = 1.0f / (float)max(cd.z, 1);
    iv.w = 1.0f / (float)max(cd.w, 1);
    *(float4*)(invd + base) = iv;
  } else {
    for (int i = 0; i < 4; ++i) {
      if (base + i < NN) {
        cur[base + i] += off;
        invd[base + i] = 1.0f / (float)max(cnt_d[base + i], 1);
      }
    }
  }
}

__global__ void fill_csc_k(const int* __restrict__ ei, const float* __restrict__ ew,
                           int* __restrict__ cur_s, int4* __restrict__ e4) {
  int e = blockIdx.x * 256 + threadIdx.x;
  if (e < EE) {
    int s = ei[e], d = ei[EE + e];
    int pc = atomicAdd(&cur_s[s], 1);
    int4 v;
    v.x = s; v.y = d; v.z = __float_as_int(ew[e]); v.w = 0;
    e4[pc] = v;
  }
}

// ---------- weight precompute: all 6 W matrices -> bf16 swizzled image ----
__global__ void wpk_k(const float* __restrict__ Wl0, const float* __restrict__ Wr0,
                      const float* __restrict__ Wl1, const float* __restrict__ Wr1,
                      const float* __restrict__ Wl2, const float* __restrict__ Wr2,
                      ushort* __restrict__ wbuf) {
  int idx = blockIdx.x * 256 + threadIdx.x;  // 0..81919
  const float* W; int F, r, off;
  if (idx < 16384)      { W = Wl0; F = 128; r = idx;         off = 0; }
  else if (idx < 32768) { W = Wr0; F = 128; r = idx - 16384; off = 16384; }
  else if (idx < 49152) { W = Wl1; F = 128; r = idx - 32768; off = 32768; }
  else if (idx < 65536) { W = Wr1; F = 128; r = idx - 49152; off = 49152; }
  else if (idx < 73728) { W = Wl2; F = 64;  r = idx - 65536; off = 65536; }
  else                  { W = Wr2; F = 64;  r = idx - 73728; off = 73728; }
  int k = r / F, n = r % F;
  wbuf[off + n * 128 + ((((k >> 3) + n) & 15) << 3) + (k & 7)] = f2bf(W[k * F + n]);
}

// ---------- MFMA dual GEMM: Tlb = bnrelu(H)@Wl (bf16 chunked), Trb = ..@Wr ----
// HB16: H is bf16 [n][128] with BN(ss)+relu; else H is f32, no BN.
template <int F, bool HB16>
__global__ __launch_bounds__(256) void gemm_mfma(
    const void* __restrict__ H, const ushort* __restrict__ Wpre,
    const float* __restrict__ ss, ushort* __restrict__ Tlb,
    ushort* __restrict__ Trb) {
  __shared__ __align__(16) ushort Wt[F * 128];
  __shared__ __align__(16) ushort Hs[64 * 128];
  const int tid = threadIdx.x;
  const int nb = blockIdx.x * 64;

  if (HB16) {
    for (int i = tid; i < 64 * 16; i += 256) {
      int m = i >> 4, c = i & 15;
      int node = nb + m;
      uint4 hv = {0, 0, 0, 0};
      if (node < NN) hv = ((const uint4*)H)[(size_t)node * 16 + c];
      int gk = c * 8;
      uint* p = (uint*)&hv;
#pragma unroll
      for (int j = 0; j < 4; ++j) {
        float f0 = fmaxf(fmaf(bflo(p[j]), ss[gk + 2 * j], ss[128 + gk + 2 * j]), 0.f);
        float f1 = fmaxf(fmaf(bfhi(p[j]), ss[gk + 2 * j + 1], ss[128 + gk + 2 * j + 1]), 0.f);
        p[j] = f22bf(f0, f1);
      }
      *(uint4*)&Hs[m * 128 + (((c + m) & 15) << 3)] = hv;
    }
  } else {
    for (int i = tid; i < 64 * 32; i += 256) {
      int m = i >> 5, kq = i & 31;
      int node = nb + m;
      float4 hv = {0.f, 0.f, 0.f, 0.f};
      if (node < NN) hv = ((const float4*)H)[(size_t)node * 32 + kq];
      int c = kq >> 1;
      int base = m * 128 + (((c + m) & 15) << 3) + (kq & 1) * 4;
      ushort4 u4 = {f2bf(hv.x), f2bf(hv.y), f2bf(hv.z), f2bf(hv.w)};
      *(ushort4*)&Hs[base] = u4;
    }
  }
  __syncthreads();

  const int lane = tid & 63;
  const int w = tid >> 6;
  const int col = lane & 15;
  const int quad = lane >> 4;
  const int m = w * 16 + col;

  bf16x8 afrag[4];
#pragma unroll
  for (int s = 0; s < 4; ++s) {
    int c = s * 4 + quad;
    afrag[s] = *(const bf16x8*)&Hs[m * 128 + (((c + m) & 15) << 3)];
  }

  for (int phase = 0; phase < 2; ++phase) {
    const uint4* src = (const uint4*)(Wpre + phase * F * 128);
    __syncthreads();
    for (int i = tid; i < F * 16; i += 256) ((uint4*)Wt)[i] = src[i];
    __syncthreads();
#pragma unroll 2
    for (int ct = 0; ct < F / 16; ++ct) {
      int n = ct * 16 + col;
      f32x4 acc = {0.f, 0.f, 0.f, 0.f};
#pragma unroll
      for (int s = 0; s < 4; ++s) {
        int c = s * 4 + quad;
        bf16x8 b = *(const bf16x8*)&Wt[n * 128 + (((c + n) & 15) << 3)];
        acc = __builtin_amdgcn_mfma_f32_16x16x32_bf16(afrag[s], b, acc, 0, 0, 0);
      }
      int nodeb = nb + w * 16 + quad * 4;
#pragma unroll
      for (int r = 0; r < 4; ++r) {
        int node = nodeb + r;
        if (node < NN) {
          int cc = ct * 16 + col;
          if (phase == 0) {
            Tlb[(size_t)(cc >> 5) * NN * 32 + (size_t)node * 32 + (cc & 31)] = f2bf(acc[r]);
          } else {
            Trb[(size_t)node * F + cc] = f2bf(acc[r]);
          }
        }
      }
    }
  }
}

// ---------- edge-parallel aggregation via HW pk-bf16 atomics ----------
// At the measured atomic roofline (~0.94 RMW/clk/slice) — structural floor.
template <int F>
__global__ __launch_bounds__(256, 8) void edge_atomic(
    const ushort* __restrict__ Tlb, const int4* __restrict__ e4,
    void* __restrict__ agg) {
  constexpr int L = F / 2;
  int gid = blockIdx.x * 256 + threadIdx.x;
  int e = gid / L;
  int cp = gid % L;
  if (e >= EE) return;
  int4 p = e4[e];
  float w = __int_as_float(p.z);
  int chunk = cp >> 4, coff = cp & 15;
  uint t = ((const uint*)Tlb)[(size_t)chunk * NN * 16 + (size_t)p.x * 16 + coff];
  float f0 = w * bflo(t);
  float f1 = w * bfhi(t);
#if USE_PK
  bf2v v;
  v.x = (short)f2bf(f0);
  v.y = (short)f2bf(f1);
  __builtin_amdgcn_global_atomic_fadd_v2bf16((bf2v*)((char*)agg + ((size_t)p.y * L + cp) * 4), v);
#else
  float* a = (float*)agg + ((size_t)p.y * L + cp) * 2;
  atomicAdd(a, f0);
  atomicAdd(a + 1, f1);
#endif
}

// ---------- combine: out = agg*invd + Trb + bias (+BN stats; zero agg) ----
// OUTF32: write f32 (final layer to d_out); else pack bf16 (hpre).
template <int F, bool STATS, bool ZERO, bool OUTF32>
__global__ __launch_bounds__(256, 8) void combine(
    void* __restrict__ agg, const ushort* __restrict__ Trb,
    const float* __restrict__ invd, const float* __restrict__ bias,
    void* __restrict__ outp, float* __restrict__ statsb) {
  constexpr int L = F / 2;
  constexpr int NPI = 256 / L;
  constexpr int NPB = 40;  // 50000/40 = 1250 blocks exact
  const int tid = threadIdx.x;
  const int cp = tid % L;
  const int c = 2 * cp;
  const int nl = tid / L;
  const int n0 = blockIdx.x * NPB;
  const float bx = bias[c], by = bias[c + 1];
  float2 S = {0.f, 0.f}, Q = {0.f, 0.f};
#pragma unroll
  for (int it = 0; it < NPB / NPI; ++it) {
    int n = n0 + it * NPI + nl;
    float a0, a1;
#if USE_PK
    uint t = ((uint*)agg)[(size_t)n * L + cp];
    a0 = bflo(t);
    a1 = bfhi(t);
    if (ZERO) ((uint*)agg)[(size_t)n * L + cp] = 0;
#else
    float2 af = ((float2*)agg)[(size_t)n * L + cp];
    a0 = af.x;
    a1 = af.y;
    if (ZERO) { float2 z = {0.f, 0.f}; ((float2*)agg)[(size_t)n * L + cp] = z; }
#endif
    float iv = invd[n];
    uint tb = ((const uint*)Trb)[(size_t)n * L + cp];
    float2 v;
    v.x = fmaf(a0, iv, bflo(tb) + bx);
    v.y = fmaf(a1, iv, bfhi(tb) + by);
    if (OUTF32) *(float2*)((float*)outp + (size_t)n * F + c) = v;
    else ((uint*)outp)[(size_t)n * L + cp] = f22bf(v.x, v.y);
    if constexpr (STATS) {
      S.x += v.x; S.y += v.y;
      Q.x += v.x * v.x; Q.y += v.y * v.y;
    }
  }
  if constexpr (STATS) {
    __shared__ float2 sS[4][L];
    __shared__ float2 sQ[4][L];
    const int wid = tid >> 6, wl = tid & 63;
    if constexpr (L == 64) {
      sS[wid][wl] = S;
      sQ[wid][wl] = Q;
    } else {
      S.x += __shfl_xor(S.x, 32, 64); S.y += __shfl_xor(S.y, 32, 64);
      Q.x += __shfl_xor(Q.x, 32, 64); Q.y += __shfl_xor(Q.y, 32, 64);
      if (wl < 32) { sS[wid][wl] = S; sQ[wid][wl] = Q; }
    }
    __syncthreads();
    if (tid < L) {
      float2 Sa = sS[0][tid], Qa = sQ[0][tid];
#pragma unroll
      for (int w2 = 1; w2 < 4; ++w2) {
        Sa.x += sS[w2][tid].x; Sa.y += sS[w2][tid].y;
        Qa.x += sQ[w2][tid].x; Qa.y += sQ[w2][tid].y;
      }
      float* sb = statsb + (size_t)(blockIdx.x & (SREP - 1)) * 256;
      int col = 2 * tid;
      atomicAdd(&sb[col], Sa.x);
      atomicAdd(&sb[col + 1], Sa.y);
      atomicAdd(&sb[128 + col], Qa.x);
      atomicAdd(&sb[128 + col + 1], Qa.y);
    }
  }
}

// ---------- BN finalize: reduce SREP replicas, then zero them ----------
__global__ void bn_fin(float* __restrict__ statsb, const float* __restrict__ gamma,
                       const float* __restrict__ beta, float* __restrict__ ss) {
  int f = threadIdx.x;
  float sum = 0.f, sq = 0.f;
#pragma unroll 8
  for (int r = 0; r < SREP; ++r) {
    sum += statsb[r * 256 + f];
    sq  += statsb[r * 256 + 128 + f];
    statsb[r * 256 + f] = 0.f;
    statsb[r * 256 + 128 + f] = 0.f;
  }
  float mu = sum * (1.0f / (float)NN);
  float ex2 = sq * (1.0f / (float)NN);
  float var = ex2 - mu * mu;
  float sc = gamma[f] * rsqrtf(var + 1e-5f);
  ss[f] = sc;
  ss[128 + f] = beta[f] - mu * sc;
}

extern "C" void kernel_launch(void* const* d_in, const int* in_sizes, int n_in,
                              void* d_out, int out_size, void* d_ws, size_t ws_size,
                              hipStream_t stream) {
  (void)in_sizes; (void)n_in; (void)out_size; (void)ws_size;
  const float* x   = (const float*)d_in[0];
  const int*   ei  = (const int*)d_in[1];
  const float* ew  = (const float*)d_in[2];
  const float* Wl0 = (const float*)d_in[3];
  const float* Wr0 = (const float*)d_in[4];
  const float* b0  = (const float*)d_in[5];
  const float* Wl1 = (const float*)d_in[6];
  const float* Wr1 = (const float*)d_in[7];
  const float* b1  = (const float*)d_in[8];
  const float* Wl2 = (const float*)d_in[9];
  const float* Wr2 = (const float*)d_in[10];
  const float* b2  = (const float*)d_in[11];
  const float* g0  = (const float*)d_in[12];
  const float* be0 = (const float*)d_in[13];
  const float* g1  = (const float*)d_in[14];
  const float* be1 = (const float*)d_in[15];
  float* out = (float*)d_out;

  size_t off = 0;
  auto alloc = [&](size_t b) -> void* {
    void* p = (char*)d_ws + off;
    off += (b + 255) & ~(size_t)255;
    return p;
  };
  ushort* tlb  = (ushort*)alloc((size_t)NN * 128 * 2);  // 12.8 MB
  ushort* trb  = (ushort*)alloc((size_t)NN * 128 * 2);  // 12.8 MB
  ushort* hpre = (ushort*)alloc((size_t)NN * 128 * 2);  // 12.8 MB (bf16)
#if USE_PK
  const size_t AGG_B = (size_t)NN * 128 * 2;
#else
  const size_t AGG_B = (size_t)NN * 128 * 4;
#endif
  void* agg    = alloc((size_t)NN * 128 * 4);           // 25.6 MB
  int4* e4     = (int4*)alloc((size_t)EE * 16);         // 9.6 MB
  ushort* wbuf = (ushort*)alloc(81920 * 2);             // 160 KB
  int*  cnts   = (int*)alloc((size_t)NN * 2 * 4);
  int*  cnt_s  = cnts;
  int*  cnt_d  = cnts + NN;
  int*  cur_s  = (int*)alloc((size_t)NN * 4);
  int*  bsum   = (int*)alloc(SCB * 4);
  float* invd  = (float*)alloc((size_t)NN * 4);
  float* statsb = (float*)alloc((size_t)SREP * 256 * 4);
  float* ssb   = (float*)alloc(256 * 4);

  const int EB = (EE + 255) / 256;
  const int GEMMB = (NN + 63) / 64;  // 782

  // ---- prep
  hipMemsetAsync(cnts, 0, (size_t)NN * 2 * 4, stream);
  hipMemsetAsync(agg, 0, AGG_B, stream);
  hipMemsetAsync(statsb, 0, (size_t)SREP * 256 * 4, stream);
  count2_k<<<EB, 256, 0, stream>>>(ei, cnt_s, cnt_d);
  wpk_k<<<320, 256, 0, stream>>>(Wl0, Wr0, Wl1, Wr1, Wl2, Wr2, wbuf);
  scanA_k<<<SCB, 256, 0, stream>>>(cnt_s, cur_s, bsum);
  scanB_k<<<1, 64, 0, stream>>>(bsum);
  scanC_k<<<SCB, 256, 0, stream>>>(cur_s, bsum, cnt_d, invd);
  fill_csc_k<<<EB, 256, 0, stream>>>(ei, ew, cur_s, e4);

  const int EG128 = (int)(((size_t)EE * 64 + 255) / 256);
  const int EG64  = (int)(((size_t)EE * 32 + 255) / 256);

  // ---- layer 0 (H = x f32, no BN)
  gemm_mfma<128, false><<<GEMMB, 256, 0, stream>>>(x, wbuf, nullptr, tlb, trb);
  edge_atomic<128><<<EG128, 256, 0, stream>>>(tlb, e4, agg);
  combine<128, true, true, false><<<NN / 40, 256, 0, stream>>>(agg, trb, invd, b0, hpre, statsb);
  bn_fin<<<1, 128, 0, stream>>>(statsb, g0, be0, ssb);

  // ---- layer 1 (H = hpre bf16, BN0+ReLU in staging; agg pre-zeroed by combine)
  gemm_mfma<128, true><<<GEMMB, 256, 0, stream>>>(hpre, wbuf + 32768, ssb, tlb, trb);
  edge_atomic<128><<<EG128, 256, 0, stream>>>(tlb, e4, agg);
  combine<128, true, true, false><<<NN / 40, 256, 0, stream>>>(agg, trb, invd, b1, hpre, statsb);
  bn_fin<<<1, 128, 0, stream>>>(statsb, g1, be1, ssb);

  // ---- layer 2 (H = hpre bf16, BN1+ReLU in staging; out f32 to d_out)
  gemm_mfma<64, true><<<GEMMB, 256, 0, stream>>>(hpre, wbuf + 65536, ssb, tlb, trb);
  edge_atomic<64><<<EG64, 256, 0, stream>>>(tlb, e4, agg);
  combine<64, false, false, true><<<NN / 40, 256, 0, stream>>>(agg, trb, invd, b2, out, nullptr);
}